// Round 3
// baseline (462.152 us; speedup 1.0000x reference)
//
#include <hip/hip_runtime.h>

#define KK 21
#define HH 512
#define WW 512
#define CC 3
#define BB 32
#define TILE_Y 64
#define TILE_X 128
#define SROWS 84        // TILE_Y + 20
#define SCOLS 160       // staged cols: TILE_X + 20, padded to 160 (A-frag s=8 reads to lc=159)
#define SSTRIDE 168     // ushort elems/row; 336 B = 21*16B, odd multiple of 16B -> conflict-free
#define NBT 21504       // s_Bt elems: 21 kh * 2 halves * 4 q * 16 n * 8 j

typedef __attribute__((ext_vector_type(8))) short short8;
typedef __attribute__((ext_vector_type(4))) float floatx4;

__device__ __forceinline__ unsigned short f2bf(float f) {
    union { float f; unsigned u; } v; v.f = f;
    unsigned r = v.u + 0x7FFF + ((v.u >> 16) & 1);   // RNE
    return (unsigned short)(r >> 16);
}

__global__ __launch_bounds__(256, 2) void dwconv_mfma(
    const float* __restrict__ x,
    const float* __restrict__ ker,
    float* __restrict__ out)
{
    __shared__ __align__(16) unsigned short s_in[SROWS * SSTRIDE];  // 28224 B
    __shared__ __align__(16) unsigned short s_Bt[NBT];              // 43008 B

    const int tiles = (HH / TILE_Y) * (WW / TILE_X);   // 32
    const int bc = blockIdx.x / tiles;                  // 0..95
    const int t  = blockIdx.x % tiles;
    const int ty0 = (t / (WW / TILE_X)) * TILE_Y;
    const int tx0 = (t % (WW / TILE_X)) * TILE_X;
    const int b = bc / CC;

    const float* __restrict__ xp = x + (size_t)bc * HH * WW;
    const float* __restrict__ kp = ker + (size_t)b * KK * KK;
    const int tid = threadIdx.x;

    // ---- build banded B matrices, chunk-major: el = (((kh*2+h)*4+q)*16+n)*8+j ----
    // B1[c][j] = K[kh][c-j]    for 0 <= c-j < 16   (kw 0..15)
    // B2[c][j] = K[kh][16+c-j] for 0 <= c-j < 5    (kw 16..20),  c = q*8+j', n = j
    for (int e = tid; e < NBT; e += 256) {
        const int j  = e & 7;
        const int n  = (e >> 3) & 15;
        const int q  = (e >> 7) & 3;
        const int h  = (e >> 9) & 1;
        const int kh = e >> 10;
        const int c  = q * 8 + j;
        const int d  = c - n;
        float v = 0.0f;
        if (h == 0) { if (d >= 0 && d < 16) v = kp[kh * KK + d]; }
        else        { if (d >= 0 && d < 5)  v = kp[kh * KK + 16 + d]; }
        s_Bt[e] = f2bf(v);
    }

    // ---- stage 84x160 input window as bf16 (zero beyond image) ----
    for (int i = tid; i < SROWS * SCOLS; i += 256) {
        const int ly = i / SCOLS;
        const int lc = i - ly * SCOLS;
        const int gy = ty0 - 10 + ly;
        const int gx = tx0 - 10 + lc;
        float v = 0.0f;
        if (gy >= 0 && gy < HH && gx >= 0 && gx < WW) v = xp[gy * WW + gx];
        s_in[ly * SSTRIDE + lc] = f2bf(v);
    }
    __syncthreads();

    const int lane = tid & 63;
    const int wv   = tid >> 6;       // wave 0..3 -> output rows 16*wv..+15
    const int mrow = lane & 15;      // A's m / B's n / D's col
    const int qd   = lane >> 4;      // k-chunk / D row group

    floatx4 acc[8];
#pragma unroll
    for (int tt = 0; tt < 8; ++tt) acc[tt] = (floatx4){0.f, 0.f, 0.f, 0.f};

#pragma unroll 1
    for (int kh = 0; kh < KK; ++kh) {
        // A-frags: 9 overlapping 16x32 windows at col offsets 16*s
        const unsigned short* arow = s_in + (16 * wv + kh + mrow) * SSTRIDE + 8 * qd;
        short8 a[9];
#pragma unroll
        for (int s = 0; s < 9; ++s) a[s] = *(const short8*)(arow + 16 * s);

        // B-frags (half 1 and half 2) for this kh
        const unsigned short* bb = s_Bt + (kh * 128 + qd * 16 + mrow) * 8;
        const short8 b1 = *(const short8*)(bb);
        const short8 b2 = *(const short8*)(bb + 512);

#pragma unroll
        for (int tt = 0; tt < 8; ++tt) {
            acc[tt] = __builtin_amdgcn_mfma_f32_16x16x32_bf16(a[tt],     b1, acc[tt], 0, 0, 0);
            acc[tt] = __builtin_amdgcn_mfma_f32_16x16x32_bf16(a[tt + 1], b2, acc[tt], 0, 0, 0);
        }
    }

    // ---- epilogue: D layout col=lane&15, row=(lane>>4)*4+reg ----
    float* __restrict__ op = out + (size_t)bc * HH * WW;
#pragma unroll
    for (int tt = 0; tt < 8; ++tt) {
#pragma unroll
        for (int r = 0; r < 4; ++r) {
            const int y = ty0 + 16 * wv + qd * 4 + r;
            const int xcol = tx0 + 16 * tt + mrow;
            op[y * WW + xcol] = acc[tt][r];
        }
    }
}

extern "C" void kernel_launch(void* const* d_in, const int* in_sizes, int n_in,
                              void* d_out, int out_size, void* d_ws, size_t ws_size,
                              hipStream_t stream) {
    const float* x   = (const float*)d_in[0];
    const float* ker = (const float*)d_in[1];
    float* out = (float*)d_out;

    const int tiles = (HH / TILE_Y) * (WW / TILE_X);   // 32
    const int nblocks = BB * CC * tiles;               // 3072

    dwconv_mfma<<<nblocks, 256, 0, stream>>>(x, ker, out);
}

// Round 4
// 242.898 us; speedup vs baseline: 1.9027x; 1.9027x over previous
//
#include <hip/hip_runtime.h>

#define KK 21
#define HH 512
#define WW 512
#define CC 3
#define BB 32
#define TILE_Y 64
#define TILE_X 128
#define SROWS 84        // TILE_Y + 20
#define SSTRIDE 168     // ushort elems/row; 336 B = odd multiple of 16B -> conflict-free A reads
#define NB_PER_B 21504  // per-batch B-frag elems: 21 kh * 2 halves * 512
#define NCHUNK 41       // float4 chunks per staged row, covering lc in [-2, 162)

typedef __attribute__((ext_vector_type(8))) short short8;
typedef __attribute__((ext_vector_type(4))) float floatx4;

__device__ __forceinline__ unsigned short f2bf(float f) {
    union { float f; unsigned u; } v; v.f = f;
    unsigned r = v.u + 0x7FFF + ((v.u >> 16) & 1);   // RNE
    return (unsigned short)(r >> 16);
}

// ---- kernel 1: build banded-Toeplitz B fragments per batch into d_ws ----
// layout el = kh*1024 + h*512 + (q*16 + n)*8 + j   (bf16)
// B1[c][n] = K[kh][c-n] (0<=c-n<16), B2[c][n] = K[kh][16+c-n] (0<=c-n<5), c=q*8+j
__global__ __launch_bounds__(256) void build_B(
    const float* __restrict__ ker, unsigned short* __restrict__ wsB)
{
    const int b = blockIdx.x;
    const float* __restrict__ kp = ker + b * KK * KK;
    unsigned short* __restrict__ wb = wsB + (size_t)b * NB_PER_B;
    for (int e = threadIdx.x; e < NB_PER_B; e += 256) {
        const int j  = e & 7;
        const int n  = (e >> 3) & 15;
        const int q  = (e >> 7) & 3;
        const int h  = (e >> 9) & 1;
        const int kh = e >> 10;
        const int d  = q * 8 + j - n;
        float v = 0.0f;
        if (h == 0) { if (d >= 0 && d < 16) v = kp[kh * KK + d]; }
        else        { if (d >= 0 && d < 5)  v = kp[kh * KK + 16 + d]; }
        wb[e] = f2bf(v);
    }
}

// ---- kernel 2: main MFMA conv ----
__global__ __launch_bounds__(256, 5) void dwconv_mfma(
    const float* __restrict__ x,
    const unsigned short* __restrict__ wsB,
    float* __restrict__ out)
{
    __shared__ __align__(16) unsigned short s_in[SROWS * SSTRIDE];  // 28224 B

    const int tiles = (HH / TILE_Y) * (WW / TILE_X);   // 32
    const int bc = blockIdx.x / tiles;                  // 0..95
    const int t  = blockIdx.x % tiles;
    const int ty0 = (t / (WW / TILE_X)) * TILE_Y;
    const int tx0 = (t % (WW / TILE_X)) * TILE_X;
    const int b = bc / CC;

    const float* __restrict__ xp = x + (size_t)bc * HH * WW;
    const unsigned short* __restrict__ wsb = wsB + (size_t)b * NB_PER_B;
    const int tid = threadIdx.x;

    // ---- stage 84-row input window as bf16, float4 global loads ----
    // chunk k covers gx = tx0-12+4k .. +3  -> lc = 4k-2 .. 4k+1
    for (int i = tid; i < SROWS * NCHUNK; i += 256) {
        const int ly = i / NCHUNK;
        const int k  = i - ly * NCHUNK;
        const int gy = ty0 - 10 + ly;
        const int gx0 = tx0 - 12 + 4 * k;
        const int lc0 = 4 * k - 2;
        float4 v = make_float4(0.f, 0.f, 0.f, 0.f);
        if (gy >= 0 && gy < HH) {
            const float* __restrict__ rp = xp + (size_t)gy * WW;
            if (gx0 >= 0 && gx0 + 3 < WW) {
                v = *(const float4*)(rp + gx0);
            } else {
                if (gx0 + 0 >= 0 && gx0 + 0 < WW) v.x = rp[gx0 + 0];
                if (gx0 + 1 >= 0 && gx0 + 1 < WW) v.y = rp[gx0 + 1];
                if (gx0 + 2 >= 0 && gx0 + 2 < WW) v.z = rp[gx0 + 2];
                if (gx0 + 3 >= 0 && gx0 + 3 < WW) v.w = rp[gx0 + 3];
            }
        }
        const unsigned p0 = (unsigned)f2bf(v.x) | ((unsigned)f2bf(v.y) << 16);
        const unsigned p1 = (unsigned)f2bf(v.z) | ((unsigned)f2bf(v.w) << 16);
        unsigned* row = (unsigned*)&s_in[ly * SSTRIDE];     // rows 4B-aligned (168 even)
        if (lc0 >= 0) row[lc0 >> 1] = p0;                   // lc0 even
        row[(lc0 >> 1) + 1] = p1;                           // k=0 -> row[0], max lc 161 < 168
    }
    __syncthreads();

    const int lane = tid & 63;
    const int wv   = tid >> 6;       // wave 0..3 -> output rows 16*wv..+15
    const int mrow = lane & 15;      // A's m / B's n / D's col
    const int qd   = lane >> 4;      // k-chunk / D row group

    floatx4 acc[8];
#pragma unroll
    for (int tt = 0; tt < 8; ++tt) acc[tt] = (floatx4){0.f, 0.f, 0.f, 0.f};

    const unsigned short* bbase = wsb + (qd * 16 + mrow) * 8;
    short8 nb1 = *(const short8*)(bbase);
    short8 nb2 = *(const short8*)(bbase + 512);

#pragma unroll 1
    for (int kh = 0; kh < KK; ++kh) {
        const short8 b1 = nb1;
        const short8 b2 = nb2;
        // prefetch next kh's B-frags (clamped; redundant reload on last iter)
        const int khn = (kh < KK - 1) ? (kh + 1) : kh;
        nb1 = *(const short8*)(bbase + khn * 1024);
        nb2 = *(const short8*)(bbase + khn * 1024 + 512);

        // A-frags: 9 overlapping 16x32 windows at col offsets 16*s
        const unsigned short* arow = s_in + (16 * wv + kh + mrow) * SSTRIDE + 8 * qd;
        short8 a[9];
#pragma unroll
        for (int s = 0; s < 9; ++s) a[s] = *(const short8*)(arow + 16 * s);

#pragma unroll
        for (int tt = 0; tt < 8; ++tt) {
            acc[tt] = __builtin_amdgcn_mfma_f32_16x16x32_bf16(a[tt],     b1, acc[tt], 0, 0, 0);
            acc[tt] = __builtin_amdgcn_mfma_f32_16x16x32_bf16(a[tt + 1], b2, acc[tt], 0, 0, 0);
        }
    }

    // ---- epilogue: D layout col=lane&15, row=(lane>>4)*4+reg ----
    float* __restrict__ op = out + (size_t)bc * HH * WW;
#pragma unroll
    for (int tt = 0; tt < 8; ++tt) {
#pragma unroll
        for (int r = 0; r < 4; ++r) {
            const int y = ty0 + 16 * wv + qd * 4 + r;
            const int xcol = tx0 + 16 * tt + mrow;
            op[(size_t)y * WW + xcol] = acc[tt][r];
        }
    }
}

extern "C" void kernel_launch(void* const* d_in, const int* in_sizes, int n_in,
                              void* d_out, int out_size, void* d_ws, size_t ws_size,
                              hipStream_t stream) {
    const float* x   = (const float*)d_in[0];
    const float* ker = (const float*)d_in[1];
    float* out = (float*)d_out;
    unsigned short* wsB = (unsigned short*)d_ws;   // 32*21504*2 = 1,376,256 B

    build_B<<<BB, 256, 0, stream>>>(ker, wsB);

    const int tiles = (HH / TILE_Y) * (WW / TILE_X);   // 32
    const int nblocks = BB * CC * tiles;               // 3072
    dwconv_mfma<<<nblocks, 256, 0, stream>>>(x, wsB, out);
}